// Round 1
// baseline (67.140 us; speedup 1.0000x reference)
//
#include <hip/hip_runtime.h>
#include <hip/hip_bf16.h>

#define NROWS 8192
#define DIM   128
#define NPAIR (NROWS / 2)
#define CSPLIT 16
#define MREP   4           // 16-row blocks per wave -> 64 rows/wave
#define ROWS_PER_BLOCK 256 // 4 waves * 64 rows

typedef __attribute__((ext_vector_type(8))) short bf16x8;
typedef __attribute__((ext_vector_type(4))) float f32x4;

__device__ inline float exp2_fast(float x) {
#if __has_builtin(__builtin_amdgcn_exp2f)
    return __builtin_amdgcn_exp2f(x);
#else
    return exp2f(x);
#endif
}

__device__ inline unsigned short f2bf(float f) {
    unsigned int u = __float_as_uint(f);
    unsigned int r = (u + 0x7fffu + ((u >> 16) & 1u)) >> 16;
    return (unsigned short)r;
}

// Kernel 1: convert X (f32) -> Xb (bf16 as ushort), zero partial row sums.
__global__ __launch_bounds__(256) void k_convert(const float* __restrict__ X,
                                                 unsigned short* __restrict__ Xb,
                                                 float* __restrict__ partial) {
    int id = blockIdx.x * 256 + threadIdx.x;       // 0 .. 262143
    float4 v = reinterpret_cast<const float4*>(X)[id];
    ushort4 o;
    o.x = f2bf(v.x); o.y = f2bf(v.y); o.z = f2bf(v.z); o.w = f2bf(v.w);
    reinterpret_cast<ushort4*>(Xb)[id] = o;
    if (id < CSPLIT * NROWS) partial[id] = 0.0f;
}

// Kernel 2: for each row r, partial[cs][r] = sum over a 512-col chunk of
// exp(dot(X[r],X[c])/128 + 1), via bf16 MFMA 16x16x32.
__global__ __launch_bounds__(256) void k_rowsum(const unsigned short* __restrict__ Xb,
                                                float* __restrict__ partial) {
    const int wave = threadIdx.x >> 6;
    const int lane = threadIdx.x & 63;
    const int l15  = lane & 15;
    const int lhi  = lane >> 4;   // 0..3
    const int rowbase = blockIdx.x * ROWS_PER_BLOCK + wave * (MREP * 16);
    const int cs = blockIdx.y;
    const int colbase = cs * (NROWS / CSPLIT);

    // A fragments: MREP row-blocks x 4 k-blocks, 8 bf16 each (16B vector load)
    bf16x8 a[MREP][4];
#pragma unroll
    for (int m = 0; m < MREP; ++m) {
        const unsigned short* arow = Xb + (size_t)(rowbase + m * 16 + l15) * DIM;
#pragma unroll
        for (int g = 0; g < 4; ++g)
            a[m][g] = *reinterpret_cast<const bf16x8*>(arow + g * 32 + lhi * 8);
    }

    float esum[MREP][4];
#pragma unroll
    for (int m = 0; m < MREP; ++m)
#pragma unroll
        for (int j = 0; j < 4; ++j) esum[m][j] = 0.0f;

    const float L2E = 1.4426950408889634f;
    const float SCL = L2E / 128.0f;   // exp(d/128+1) = exp2(d*SCL + L2E)

    const int NTILES = (NROWS / CSPLIT) / 16;   // 32
    for (int ct = 0; ct < NTILES; ++ct) {
        const unsigned short* brow = Xb + (size_t)(colbase + ct * 16 + l15) * DIM;
        bf16x8 b[4];
#pragma unroll
        for (int g = 0; g < 4; ++g)
            b[g] = *reinterpret_cast<const bf16x8*>(brow + g * 32 + lhi * 8);
#pragma unroll
        for (int m = 0; m < MREP; ++m) {
            f32x4 d = {0.0f, 0.0f, 0.0f, 0.0f};
#pragma unroll
            for (int g = 0; g < 4; ++g)
                d = __builtin_amdgcn_mfma_f32_16x16x32_bf16(a[m][g], b[g], d, 0, 0, 0);
#pragma unroll
            for (int j = 0; j < 4; ++j)
                esum[m][j] += exp2_fast(fmaf(d[j], SCL, L2E));
        }
    }

    // Reduce the 16 column-lanes (same lhi, varying l15); write one slot per row.
#pragma unroll
    for (int m = 0; m < MREP; ++m) {
#pragma unroll
        for (int j = 0; j < 4; ++j) {
            float v = esum[m][j];
            v += __shfl_xor(v, 1, 64);
            v += __shfl_xor(v, 2, 64);
            v += __shfl_xor(v, 4, 64);
            v += __shfl_xor(v, 8, 64);
            if (l15 == 0) {
                int row = rowbase + m * 16 + lhi * 4 + j;
                partial[(size_t)cs * NROWS + row] = v;
            }
        }
    }
}

// Kernel 3: exact f32 2x2 diagonal blocks + D_pos per pair.
__global__ __launch_bounds__(256) void k_pair(const float* __restrict__ X,
                                              float* __restrict__ blocksum,
                                              float* __restrict__ dpos) {
    int p = blockIdx.x * 256 + threadIdx.x;
    if (p >= NPAIR) return;
    const float4* a = reinterpret_cast<const float4*>(X + (size_t)(2 * p) * DIM);
    const float4* b = reinterpret_cast<const float4*>(X + (size_t)(2 * p + 1) * DIM);
    float d00 = 0.f, d01 = 0.f, d11 = 0.f;
#pragma unroll 8
    for (int i = 0; i < DIM / 4; ++i) {
        float4 av = a[i], bv = b[i];
        d00 += av.x * av.x + av.y * av.y + av.z * av.z + av.w * av.w;
        d01 += av.x * bv.x + av.y * bv.y + av.z * bv.z + av.w * bv.w;
        d11 += bv.x * bv.x + bv.y * bv.y + bv.z * bv.z + bv.w * bv.w;
    }
    float D01 = d01 * (1.0f / DIM);
    float e00 = __expf(d00 * (1.0f / DIM) + 1.0f);
    float e01 = __expf(D01 + 1.0f);
    float e11 = __expf(d11 * (1.0f / DIM) + 1.0f);
    blocksum[p] = e00 + 2.0f * e01 + e11;
    dpos[p] = D01;
}

// Kernel 4: single-block deterministic reduction -> loss.
__global__ __launch_bounds__(256) void k_loss(const float* __restrict__ partial,
                                              const float* __restrict__ blocksum,
                                              const float* __restrict__ dpos,
                                              float* __restrict__ out) {
    float acc = 0.0f;
    for (int p = threadIdx.x; p < NPAIR; p += 256) {
        int r0 = 2 * p;
        float S = 0.0f;
#pragma unroll
        for (int cs = 0; cs < CSPLIT; ++cs)
            S += partial[cs * NROWS + r0] + partial[cs * NROWS + r0 + 1];
        S -= blocksum[p];
        float J = logf(1e-8f + S) - dpos[p];
        float t = fmaxf(J, 0.0f);
        acc += t * t;
    }
    __shared__ float red[4];
    float v = acc;
#pragma unroll
    for (int off = 32; off >= 1; off >>= 1) v += __shfl_down(v, off, 64);
    if ((threadIdx.x & 63) == 0) red[threadIdx.x >> 6] = v;
    __syncthreads();
    if (threadIdx.x == 0)
        out[0] = (red[0] + red[1] + red[2] + red[3]) * (1.0f / (2.0f * NPAIR));
}

extern "C" void kernel_launch(void* const* d_in, const int* in_sizes, int n_in,
                              void* d_out, int out_size, void* d_ws, size_t ws_size,
                              hipStream_t stream) {
    const float* X = (const float*)d_in[0];
    float* out = (float*)d_out;

    unsigned short* Xb = (unsigned short*)d_ws;                       // 2 MB
    float* partial = (float*)((char*)d_ws + (size_t)(2 << 20));       // 512 KB
    float* blocksum = partial + CSPLIT * NROWS;                       // 16 KB
    float* dpos = blocksum + NPAIR;                                   // 16 KB

    k_convert<<<dim3((NROWS * DIM / 4) / 256), dim3(256), 0, stream>>>(X, Xb, partial);
    k_rowsum<<<dim3(NROWS / ROWS_PER_BLOCK, CSPLIT), dim3(256), 0, stream>>>(Xb, partial);
    k_pair<<<dim3(NPAIR / 256), dim3(256), 0, stream>>>(X, blocksum, dpos);
    k_loss<<<dim3(1), dim3(256), 0, stream>>>(partial, blocksum, dpos, out);
}